// Round 1
// 80.445 us; speedup vs baseline: 1.0085x; 1.0085x over previous
//
#include <hip/hip_runtime.h>

// FeedForwardQuantum: out = relu(cos(x+theta) @ W1 + b1) @ W2 + b2
// x: [B,S,E=8] fp32, W1: [8,32], W2: [32,8]. 524288 tokens.
//
// R15: LDS-free, all-64-lane structure. Per wave: 64 tokens (2 tiles of 32),
// single pass (8192 waves, 1 pair each).
// Layer 1: two 32x32x16 f16 MFMAs sharing one A operand (W1 replicated on
// both k-halves); tile0's q enters at k=0-7 (lanes 0-31), tile1's at k=8-15
// (lanes 32-63) -> every lane loads x, computes cos, stores out.
// C(32x32) -> layer-2 B operand via 4 v_permlane32_swap per tile
// (replaces R14's 8 ds_write + 8 ds_read + lgkmcnt round trip).
// Layer 2: two chained 32x32x16 MFMAs (K=16+16 = F=32 exact); D rows 0-7
// are the real e's: half0 lane t holds e0-3, half1 lane t holds e4-7.
// Layouts (guide-verified): 32x32 C/D row=(r&3)+8*(r>>2)+4*(lane>>5),
// col=lane&31; A/B 32x32x16: m(n)=lane&31, k=(lane>>5)*8+j.
// permlane32_swap(x,y): x' = {x.lo | y.lo}, y' = {x.hi | y.hi} across the
// lane<32 / lane>=32 halves.

#define TPB 256

typedef _Float16 h8  __attribute__((ext_vector_type(8)));
typedef __fp16   fp16x2 __attribute__((ext_vector_type(2)));
typedef float    f16v __attribute__((ext_vector_type(16)));
typedef int      i2  __attribute__((ext_vector_type(2)));

union H2I { fp16x2 h; int i; };
union I4H8 { int i[4]; h8 h; };

__device__ __forceinline__ int pack_f16(float a, float b) {
    H2I u;
    u.h = __builtin_amdgcn_cvt_pkrtz(a, b);   // low=a, high=b (same as R14)
    return u.i;
}

// relu + pack H^T (32x32 D layout) -> layer-2 B operands via permlane32_swap,
// two chained MFMAs, store token's 4 floats (this lane's e-quad).
__device__ __forceinline__ void layer2_store(
    const f16v c1, const h8 a2a, const h8 a2b, const f16v c20,
    float4* __restrict__ outv, int tok, int halfidx)
{
    // pk[i] = f16pair(f_{2i}, f_{2i+1}) where f_r = (r&3)+8*(r>>2)+4*half
    int pk[8];
#pragma unroll
    for (int i = 0; i < 8; ++i)
        pk[i] = pack_f16(fmaxf(c1[2 * i], 0.0f), fmaxf(c1[2 * i + 1], 0.0f));

    // B2a needs per-lane k=8*half+j -> half0: f0..7, half1: f8..15
    // B2b: half0: f16..23, half1: f24..31
    i2 s0 = __builtin_amdgcn_permlane32_swap(pk[0], pk[2], false, false);
    i2 s1 = __builtin_amdgcn_permlane32_swap(pk[1], pk[3], false, false);
    i2 s2 = __builtin_amdgcn_permlane32_swap(pk[4], pk[6], false, false);
    i2 s3 = __builtin_amdgcn_permlane32_swap(pk[5], pk[7], false, false);

    I4H8 ba, bb;
    ba.i[0] = s0.x; ba.i[1] = s1.x; ba.i[2] = s0.y; ba.i[3] = s1.y;
    bb.i[0] = s2.x; bb.i[1] = s3.x; bb.i[2] = s2.y; bb.i[3] = s3.y;

    f16v o = __builtin_amdgcn_mfma_f32_32x32x16_f16(a2a, ba.h, c20, 0, 0, 0);
    o      = __builtin_amdgcn_mfma_f32_32x32x16_f16(a2b, bb.h, o,   0, 0, 0);

    // D row e = r + 4*half for r<4; col = token. half0 -> floats 0-3, half1 -> 4-7.
    outv[2 * tok + halfidx] = make_float4(o[0], o[1], o[2], o[3]);
}

__global__ __launch_bounds__(TPB) void ffq_kernel(
    const float4* __restrict__ xv,      // x as float4 pairs: token g -> xv[2g], xv[2g+1]
    const float*  __restrict__ theta,   // [8]
    const float*  __restrict__ w1,      // [8][32] row-major
    const float*  __restrict__ b1,      // [32]
    const float*  __restrict__ w2,      // [32][8] row-major
    const float*  __restrict__ b2,      // [8]
    float4*       __restrict__ outv,    // out as float4 pairs
    int npair, int nwaves)
{
    const int tid  = threadIdx.x;
    const int lane = tid & 63;
    const int half = lane >> 5;
    const int l31  = lane & 31;

    // ---- one-time setup (all cached small arrays) ----
    // A1 (32x32x16): A[m=f=l31][k=8*half+j] = W1[j][f]  (replicated k-halves)
    h8 a1;
#pragma unroll
    for (int j = 0; j < 8; ++j)
        a1[j] = (_Float16)w1[j * 32 + l31];

    // A2a: A[m=e=l31][k=8*half+j] = W2[f=k][e];  A2b: f = 16+k
    h8 a2a, a2b;
#pragma unroll
    for (int j = 0; j < 8; ++j) {
        a2a[j] = (l31 < 8) ? (_Float16)w2[(8 * half + j) * 8 + l31]      : (_Float16)0;
        a2b[j] = (l31 < 8) ? (_Float16)w2[(16 + 8 * half + j) * 8 + l31] : (_Float16)0;
    }

    // C1 init: c10[r] = b1[(r&3) + 8*(r>>2) + 4*half] -> 4x float4 loads
    f16v c10;
#pragma unroll
    for (int g = 0; g < 4; ++g) {
        const float4 v = ((const float4*)b1)[2 * g + half];
        c10[4 * g + 0] = v.x; c10[4 * g + 1] = v.y;
        c10[4 * g + 2] = v.z; c10[4 * g + 3] = v.w;
    }

    // C2 init: rows e = r + 4*half for r<4 real; rest 0 (A2 rows m>=8 are 0)
    f16v c20;
#pragma unroll
    for (int r = 0; r < 16; ++r) c20[r] = 0.0f;
    {
        const float4 v = ((const float4*)b2)[half];
        c20[0] = v.x; c20[1] = v.y; c20[2] = v.z; c20[3] = v.w;
    }

    float th[8];
#pragma unroll
    for (int e = 0; e < 8; ++e) th[e] = theta[e];

    const int wid = blockIdx.x * (TPB / 64) + (tid >> 6);

    for (int pair = wid; pair < npair; pair += nwaves) {
        // all 64 lanes load one token: 2KB/wave, fully coalesced
        const int tok = pair * 64 + lane;
        const float4 xa = xv[2 * tok];
        const float4 xb = xv[2 * tok + 1];

        // q[j] = cos(x[j] + theta[j]), f16 (RTN casts, same numerics as R14)
        I4H8 q;
        q.h[0] = (_Float16)__cosf(xa.x + th[0]);
        q.h[1] = (_Float16)__cosf(xa.y + th[1]);
        q.h[2] = (_Float16)__cosf(xa.z + th[2]);
        q.h[3] = (_Float16)__cosf(xa.w + th[3]);
        q.h[4] = (_Float16)__cosf(xb.x + th[4]);
        q.h[5] = (_Float16)__cosf(xb.y + th[5]);
        q.h[6] = (_Float16)__cosf(xb.z + th[6]);
        q.h[7] = (_Float16)__cosf(xb.w + th[7]);

        // B1 for tile0: lanes 0-31 supply k=0-7; tile1: lanes 32-63 supply k=8-15
        I4H8 b0, b1q;
#pragma unroll
        for (int p = 0; p < 4; ++p) {
            b0.i[p]  = half ? 0 : q.i[p];
            b1q.i[p] = half ? q.i[p] : 0;
        }

        // H^T[f][t] = W1^T.Q^T + b1, one MFMA per 32-token tile
        const f16v c1_0 = __builtin_amdgcn_mfma_f32_32x32x16_f16(a1, b0.h,  c10, 0, 0, 0);
        const f16v c1_1 = __builtin_amdgcn_mfma_f32_32x32x16_f16(a1, b1q.h, c10, 0, 0, 0);

        layer2_store(c1_0, a2a, a2b, c20, outv, pair * 64 + l31,      half);
        layer2_store(c1_1, a2a, a2b, c20, outv, pair * 64 + 32 + l31, half);
    }
}

extern "C" void kernel_launch(void* const* d_in, const int* in_sizes, int n_in,
                              void* d_out, int out_size, void* d_ws, size_t ws_size,
                              hipStream_t stream) {
    const float* x     = (const float*)d_in[0];
    const float* theta = (const float*)d_in[1];
    const float* w1    = (const float*)d_in[2];
    const float* b1    = (const float*)d_in[3];
    const float* w2    = (const float*)d_in[4];
    const float* b2    = (const float*)d_in[5];
    float* out = (float*)d_out;

    const int ntok  = in_sizes[0] / 8;          // 524288
    const int npair = ntok / 64;                // 8192 (exact)
    const int wpb   = TPB / 64;                 // 4 waves/block
    const int grid  = (npair + wpb - 1) / wpb;  // 2048 blocks -> 1 pair/wave
    const int nwaves = grid * wpb;

    ffq_kernel<<<grid, TPB, 0, stream>>>(
        (const float4*)x, theta, w1, b1, w2, b2, (float4*)out, npair, nwaves);
}